// Round 7
// baseline (351.637 us; speedup 1.0000x reference)
//
#include <hip/hip_runtime.h>

// Fused RK4 step for 2D Burgers-like PDE, periodic BCs, radius-2 stencils.
// R9: 512-thread blocks for 2-block/CU residency + exact wave balance.
//  Evidence chain: R8 (waves_per_eu(4,4), forced 1 block) REGRESSED 131->143
//  => partial 2nd-block residency was helping. R4 (VGPR=32) hit 82% occupancy
//  => 2 blocks co-reside when VGPR allows. At VGPR=64 a 16-wave block needs
//  the entire 512-reg/SIMD pool -> never doubles. Fix: 8-wave blocks.
//  - Same 64x64 tile, LCOLS=100 bank-perfect layout, async global_load_lds
//    staging, center-in-register, exact regions [all harness-validated].
//  - Ownership: dense core = 2 quads/thread (8-row x 16-qc band per wave),
//    no predicates, active all 4 stages; ring = R7's death-ordered 496 quads
//    as slot 3, active for tid < {496,272,200,0} -- per-stage body-times
//    {3,3,3,2} for work {1520,1296,1224,1024}/512 => 90% balance vs 71%.
//  - Ring quads carry NO au/av (never produce output): fewer regs + FMAs.
//  - __launch_bounds__(512,4): 2 blocks/CU target, VGPR cap 128 (no spill at
//    ~100 est. pressure). Block B overlaps block A's barriers/staging.

typedef float f4 __attribute__((ext_vector_type(4)));
typedef float f2 __attribute__((ext_vector_type(2)));

#define LCOLS 100           // output cols at staged cols [16,80)
#define NFLD  8192          // 80*100 = 8000 staged + 192 dead tail (chunk pad)
#define NT    512

#define GLOAD16(gp, lp) __builtin_amdgcn_global_load_lds(                      \
    (const __attribute__((address_space(1))) void*)(gp),                       \
    (__attribute__((address_space(3))) void*)(lp), 16, 0, 0)

// One quad (4 cells) of one RK stage. S=0 reads center from LDS; S>=1 uses the
// in-register center su/sv. ACC: maintain RK accumulator (core quads only).
// S==3 emits final output into ou/ov.
template<int S, bool ACC>
__device__ __forceinline__ void quad_stage(
    const float* tu, const float* tv, int l,
    float nu, float UA, float UB, float VA, float VB,
    f4& ku, f4& kv, f4& au, f4& av, f4& su, f4& sv, f4& ou, f4& ov)
{
    const float csub = (S==0) ? 0.f : ((S==3) ? 0.5f : 0.25f);
    const float cadd = (S<=1) ? 0.25f : ((S==2) ? 0.5f : 0.f);
    const float wgt  = (S==1 || S==2) ? 2.f : 1.f;
    const float d1 = 800.f/12.f;          // (8/12)/DX
    const float d2 = 100.f/12.f;          // (1/12)/DX
    const float a1 = (4.f/3.f)*1.0e4f;    // (4/3)/DX^2
    const float a2 = -(1.f/12.f)*1.0e4f;  // (-1/12)/DX^2
    const float a0 = -5.0e4f;             // -5/DX^2 (both axes center)

    f4 ucc, vcc;
    if (S == 0) { ucc = *(const f4*)(tu+l); vcc = *(const f4*)(tv+l); }
    else        { ucc = su;                 vcc = sv; }
    f2 ul2 = *(const f2*)(tu+l-2);
    f2 ur2 = *(const f2*)(tu+l+4);
    f4 un1 = *(const f4*)(tu+l-LCOLS);
    f4 us1 = *(const f4*)(tu+l+LCOLS);
    f4 un2 = *(const f4*)(tu+l-2*LCOLS);
    f4 us2 = *(const f4*)(tu+l+2*LCOLS);
    f2 vl2 = *(const f2*)(tv+l-2);
    f2 vr2 = *(const f2*)(tv+l+4);
    f4 vn1 = *(const f4*)(tv+l-LCOLS);
    f4 vs1 = *(const f4*)(tv+l+LCOLS);
    f4 vn2 = *(const f4*)(tv+l-2*LCOLS);
    f4 vs2 = *(const f4*)(tv+l+2*LCOLS);
    float hu[8] = {ul2[0],ul2[1],ucc[0],ucc[1],ucc[2],ucc[3],ur2[0],ur2[1]};
    float hv[8] = {vl2[0],vl2[1],vcc[0],vcc[1],vcc[2],vcc[3],vr2[0],vr2[1]};
#pragma unroll
    for (int k = 0; k < 4; ++k) {
        float u = hu[k+2], v = hv[k+2];
        // row-direction derivative (axis 2) = reference K_DX
        float urow = d1*(us1[k]-un1[k]) + d2*(un2[k]-us2[k]);
        float vrow = d1*(vs1[k]-vn1[k]) + d2*(vn2[k]-vs2[k]);
        // col-direction derivative (axis 3) = reference K_DY
        float ucol = d1*(hu[k+3]-hu[k+1]) + d2*(hu[k]-hu[k+4]);
        float vcol = d1*(hv[k+3]-hv[k+1]) + d2*(hv[k]-hv[k+4]);
        float ulap = a1*((un1[k]+us1[k])+(hu[k+1]+hu[k+3]))
                   + a2*((un2[k]+us2[k])+(hu[k]+hu[k+4])) + a0*u;
        float vlap = a1*((vn1[k]+vs1[k])+(hv[k+1]+hv[k+3]))
                   + a2*((vn2[k]+vs2[k])+(hv[k]+hv[k+4])) + a0*v;
        float fu = nu*ulap + UA*(u*urow) + UB*(v*ucol);
        float fv = nu*vlap + VA*(u*vrow) + VB*(v*vcol);
        float kuold = ku[k], kvold = kv[k];
        if (S == 3) {
            // u0 = t3 - DT*k3 ; out = u0 + (DT/6)*(k1+2k2+2k3+k4)
            ou[k] = (u - 0.5f*kuold) + (1.f/12.f)*(au[k] + fu);
            ov[k] = (v - 0.5f*kvold) + (1.f/12.f)*(av[k] + fv);
        } else {
            if (ACC) {
                au[k] += wgt*fu;
                av[k] += wgt*fv;
            }
            // t_{s+1} = u0 + cadd*k_new, with u0 = t_s - csub*k_prev
            su[k] = (u - csub*kuold) + cadd*fu;
            sv[k] = (v - csub*kvold) + cadd*fv;
            ku[k] = fu;
            kv[k] = fv;
        }
    }
}

__global__ __launch_bounds__(NT, 4)
void rk4_stencil(const float* __restrict__ h,
                 const float* __restrict__ sRe, const float* __restrict__ sUA,
                 const float* __restrict__ sUB, const float* __restrict__ sVA,
                 const float* __restrict__ sVB, float* __restrict__ out)
{
    __shared__ __align__(16) float tu[NFLD];
    __shared__ __align__(16) float tv[NFLD];

    const int tid = threadIdx.x;
    const int tc = blockIdx.x, tr = blockIdx.y, bb = blockIdx.z;

    const float Re = sRe[0], UA = sUA[0], UB = sUB[0], VA = sVA[0], VB = sVB[0];
    const float nu = 0.001f / Re;
    const f4 z4 = {0.f, 0.f, 0.f, 0.f};

    const size_t plane = 1048576;
    const float* uin = h + (size_t)(bb*2) * plane;
    const float* vin = uin + plane;
    const int base_r = tr*64 - 8  + 1024;   // pre-biased for & 1023 wrap
    const int base_c = tc*64 - 16 + 1024;   // multiple of 4 -> no f4 straddle

    // ---- async stage u0,v0: 2 fields x 32 chunks x 1024B, no predicates ----
    // chunk tail (idx >= 8000) stages wrapped-garbage rows 80/81: never read.
    {
        const int wave = tid >> 6, lane = tid & 63;
#pragma unroll
        for (int it = 0; it < 8; ++it) {
            int c = wave + 8*it;            // wave-uniform chunk id 0..63
            int fld = (c >= 32);
            int cc  = c & 31;
            int idx = 256*cc + 4*lane;      // float index into 80x100 tile
            int row = idx / LCOLS;
            int col = idx - row*LCOLS;      // multiple of 4
            int gr = (base_r + row) & 1023;
            int gc = (base_c + col) & 1023;
            const float* gp = (fld ? vin : uin) + ((size_t)gr << 10) + gc;
            float* lp = (fld ? tv : tu) + 256*cc;   // wave-uniform LDS base
            GLOAD16(gp, lp);
        }
    }
    __syncthreads();   // drains vmcnt -> tile visible

    // ---- ownership ----
    // Dense core: rows [8,72) x qc [4,20) = 1024 quads; wave = 8-row x 16-qc
    // band; thread owns 2 quads (m=0: rows 8+8w..+3, m=1: +4..+7). Lanes 0-15
    // share a row at qc stride 4 slots -> conflict-free b128 groups.
    const int wv = tid >> 6, ln = tid & 63;
    const int dqr0 = 8 + 8*wv + (ln >> 4);
    const int dqr1 = dqr0 + 4;
    const int dqc  = 4 + (ln & 15);
    const int dl0  = dqr0*LCOLS + 4*dqc;
    const int dl1  = dqr1*LCOLS + 4*dqc;

    // Ring: 496 halo quads ordered by death stage (R7 table, validated):
    //  [0,200): active s0,s1,s2 ; [200,272): s0,s1 ; [272,496): s0 only
    int rqr = 0, rqc = 0;
    if (tid < 496) {
        int i = tid;
        if      (i < 36)  { rqr = 6  + i/18;       rqc = 3 + i%18; }
        else if (i < 72)  { int t=i-36;  rqr = 72 + t/18; rqc = 3 + t%18; }
        else if (i < 136) { rqr = 8 + (i-72);      rqc = 3; }
        else if (i < 200) { rqr = 8 + (i-136);     rqc = 20; }
        else if (i < 236) { int t=i-200; rqr = 4  + t/18; rqc = 3 + t%18; }
        else if (i < 272) { int t=i-236; rqr = 74 + t/18; rqc = 3 + t%18; }
        else if (i < 312) { int t=i-272; rqr = 2  + t/20; rqc = 2 + t%20; }
        else if (i < 352) { int t=i-312; rqr = 76 + t/20; rqc = 2 + t%20; }
        else if (i < 424) { rqr = 4 + (i-352);     rqc = 2; }
        else              { rqr = 4 + (i-424);     rqc = 21; }
    }
    const int rl = rqr*LCOLS + 4*rqc;

    f4 dku0=z4, dkv0=z4, dau0=z4, dav0=z4, dsu0=z4, dsv0=z4;
    f4 dku1=z4, dkv1=z4, dau1=z4, dav1=z4, dsu1=z4, dsv1=z4;
    f4 rku=z4, rkv=z4, rsu=z4, rsv=z4;      // ring: no accumulator needed
    f4 dmy0=z4, dmy1=z4;                    // dummy au/av (ring) & ou/ov (s<3)

    // ---- stage 0 (ring active: tid < 496) ----
    quad_stage<0,true >(tu,tv,dl0, nu,UA,UB,VA,VB, dku0,dkv0,dau0,dav0,dsu0,dsv0, dmy0,dmy1);
    quad_stage<0,true >(tu,tv,dl1, nu,UA,UB,VA,VB, dku1,dkv1,dau1,dav1,dsu1,dsv1, dmy0,dmy1);
    if (tid < 496)
        quad_stage<0,false>(tu,tv,rl, nu,UA,UB,VA,VB, rku,rkv,dmy0,dmy1,rsu,rsv, dmy0,dmy1);
    __syncthreads();
    *(f4*)(tu+dl0) = dsu0; *(f4*)(tv+dl0) = dsv0;
    *(f4*)(tu+dl1) = dsu1; *(f4*)(tv+dl1) = dsv1;
    if (tid < 496) { *(f4*)(tu+rl) = rsu; *(f4*)(tv+rl) = rsv; }
    __syncthreads();

    // ---- stage 1 (ring active: tid < 272) ----
    quad_stage<1,true >(tu,tv,dl0, nu,UA,UB,VA,VB, dku0,dkv0,dau0,dav0,dsu0,dsv0, dmy0,dmy1);
    quad_stage<1,true >(tu,tv,dl1, nu,UA,UB,VA,VB, dku1,dkv1,dau1,dav1,dsu1,dsv1, dmy0,dmy1);
    if (tid < 272)
        quad_stage<1,false>(tu,tv,rl, nu,UA,UB,VA,VB, rku,rkv,dmy0,dmy1,rsu,rsv, dmy0,dmy1);
    __syncthreads();
    *(f4*)(tu+dl0) = dsu0; *(f4*)(tv+dl0) = dsv0;
    *(f4*)(tu+dl1) = dsu1; *(f4*)(tv+dl1) = dsv1;
    if (tid < 272) { *(f4*)(tu+rl) = rsu; *(f4*)(tv+rl) = rsv; }
    __syncthreads();

    // ---- stage 2 (ring active: tid < 200) ----
    quad_stage<2,true >(tu,tv,dl0, nu,UA,UB,VA,VB, dku0,dkv0,dau0,dav0,dsu0,dsv0, dmy0,dmy1);
    quad_stage<2,true >(tu,tv,dl1, nu,UA,UB,VA,VB, dku1,dkv1,dau1,dav1,dsu1,dsv1, dmy0,dmy1);
    if (tid < 200)
        quad_stage<2,false>(tu,tv,rl, nu,UA,UB,VA,VB, rku,rkv,dmy0,dmy1,rsu,rsv, dmy0,dmy1);
    __syncthreads();
    *(f4*)(tu+dl0) = dsu0; *(f4*)(tv+dl0) = dsv0;
    *(f4*)(tu+dl1) = dsu1; *(f4*)(tv+dl1) = dsv1;
    if (tid < 200) { *(f4*)(tu+rl) = rsu; *(f4*)(tv+rl) = rsv; }
    __syncthreads();

    // ---- stage 3 (core only; direct global store) ----
    {
        float* outu = out + (size_t)(bb*2) * plane;
        float* outv = outu + plane;
        f4 ou, ov;
        const int gc = tc*64 + 4*dqc - 16;             // [0,64)
        quad_stage<3,true>(tu,tv,dl0, nu,UA,UB,VA,VB, dku0,dkv0,dau0,dav0,dsu0,dsv0, ou,ov);
        int gr0 = tr*64 + (dqr0 - 8);                  // [0,64)
        *(f4*)(outu + (size_t)gr0*1024 + gc) = ou;
        *(f4*)(outv + (size_t)gr0*1024 + gc) = ov;
        quad_stage<3,true>(tu,tv,dl1, nu,UA,UB,VA,VB, dku1,dkv1,dau1,dav1,dsu1,dsv1, ou,ov);
        int gr1 = tr*64 + (dqr1 - 8);
        *(f4*)(outu + (size_t)gr1*1024 + gc) = ou;
        *(f4*)(outv + (size_t)gr1*1024 + gc) = ov;
    }
}

extern "C" void kernel_launch(void* const* d_in, const int* in_sizes, int n_in,
                              void* d_out, int out_size, void* d_ws, size_t ws_size,
                              hipStream_t stream) {
    const float* h   = (const float*)d_in[0];
    const float* sRe = (const float*)d_in[1];
    const float* sUA = (const float*)d_in[2];
    const float* sUB = (const float*)d_in[3];
    const float* sVA = (const float*)d_in[4];
    const float* sVB = (const float*)d_in[5];
    float* o = (float*)d_out;
    rk4_stencil<<<dim3(16,16,8), dim3(NT,1,1), 0, stream>>>(h, sRe, sUA, sUB, sVA, sVB, o);
}

// Round 8
// 207.686 us; speedup vs baseline: 1.6931x; 1.6931x over previous
//
#include <hip/hip_runtime.h>

// Fused RK4 step for 2D Burgers-like PDE, periodic BCs, radius-2 stencils.
// R10: persistent tile-pipelined blocks + double-buffered LDS staging.
//  Evidence chain: all spill-free variants plateau at ~131us with VALUBusy
//  ~58% and 1 block/CU (R8: forcing 1 block regressed; R4: 2 blocks need
//  VGPR~32 which spills; R7/R9: >2 quad-states spill at the 64-reg wall).
//  At 1-block residency each block start pays an EXPOSED 64 KiB staging
//  (~2.6us, ~16% of tile time) -- nothing co-resident to hide it.
//  Fix: 512 blocks x 4 tiles each; prefetch tile i+1 into the other 64 KiB
//  LDS buffer (async global_load_lds) while computing tile i. Prefetch
//  drains at the first intra-compute barrier => hidden under stage-0.
//  LDS 128 KiB dynamic (hipFuncSetAttribute opt-in) -- 1-block residency is
//  now structural, so VGPR may exceed 64 freely.
//  Compute core byte-identical to R6 (validated): LCOLS=100 bank-perfect
//  col-major quads, exact regions, center-in-register, NQ=2.

typedef float f4 __attribute__((ext_vector_type(4)));
typedef float f2 __attribute__((ext_vector_type(2)));

#define LCOLS 100           // output cols at staged cols [16,80)
#define NFLD  8192          // 80*100 = 8000 staged + 192 dead tail (chunk pad)
#define NT    1024
#define NQ    2             // 1600 quads / 1024 threads
#define NBLK  512           // blocks
#define TPB   4             // tiles per block: 512*4 = 2048 tiles

#define GLOAD16(gp, lp) __builtin_amdgcn_global_load_lds(                      \
    (const __attribute__((address_space(1))) void*)(gp),                       \
    (__attribute__((address_space(3))) void*)(lp), 16, 0, 0)

__global__ __launch_bounds__(NT, 4)
void rk4_stencil(const float* __restrict__ h,
                 const float* __restrict__ sRe, const float* __restrict__ sUA,
                 const float* __restrict__ sUB, const float* __restrict__ sVA,
                 const float* __restrict__ sVB, float* __restrict__ out)
{
    extern __shared__ __align__(16) float lds[];   // 2 buffers x 2 fields x 8192

    const int tid = threadIdx.x;
    const int bx  = blockIdx.x;

    const float Re = sRe[0], UA = sUA[0], UB = sUB[0], VA = sVA[0], VB = sVB[0];
    const float nu = 0.001f / Re;

    const float d1 = 800.f/12.f;          // (8/12)/DX
    const float d2 = 100.f/12.f;          // (1/12)/DX
    const float a1 = (4.f/3.f)*1.0e4f;    // (4/3)/DX^2
    const float a2 = -(1.f/12.f)*1.0e4f;  // (-1/12)/DX^2
    const float a0 = -5.0e4f;             // -5/DX^2 (both axes center)

    const f4 z4 = {0.f, 0.f, 0.f, 0.f};
    const size_t plane = 1048576;

    // ---- async stage one tile's u0,v0 into buffer `buf` ----
    // 2 fields x 32 chunks x 1024B, no predicates; tail (idx>=8000) stages
    // wrapped-garbage rows 80/81: never read.
    auto stage_tile = [&](int t, int buf) {
        const int tc = t & 15, tr = (t >> 4) & 15, bb = t >> 8;
        const float* uin = h + (size_t)(bb*2) * plane;
        const float* vin = uin + plane;
        const int base_r = tr*64 - 8  + 1024;   // pre-biased for & 1023 wrap
        const int base_c = tc*64 - 16 + 1024;   // multiple of 4 -> no straddle
        float* tub = lds + (buf ? 2*NFLD : 0);
        float* tvb = tub + NFLD;
        const int wave = tid >> 6, lane = tid & 63;
#pragma unroll
        for (int it = 0; it < 4; ++it) {
            int c = wave + 16*it;           // wave-uniform chunk id 0..63
            int fld = (c >= 32);
            int cc  = c & 31;
            int idx = 256*cc + 4*lane;      // float index into 80x100 tile
            int row = idx / LCOLS;
            int col = idx - row*LCOLS;      // multiple of 4
            int gr = (base_r + row) & 1023;
            int gc = (base_c + col) & 1023;
            const float* gp = (fld ? vin : uin) + ((size_t)gr << 10) + gc;
            float* lp = (fld ? tvb : tub) + 256*cc;   // wave-uniform LDS base
            GLOAD16(gp, lp);
        }
    };

    // ownership (COLUMN-MAJOR, tile-independent): q = tid + NT*j;
    // qr = q%80, qc = q/80 + 2. Aligned 8-lane groups share qc with 8
    // consecutive qr -> conflict-free b128 groups.
    int  lidx[NQ]; bool has[NQ]; int qrA[NQ], qcA[NQ];
#pragma unroll
    for (int j = 0; j < NQ; ++j) {
        int q = tid + NT*j;
        has[j] = (j == 0) || (q < 1600);
        int qr = q % 80, qc = q / 80 + 2;
        qrA[j] = qr; qcA[j] = qc;
        lidx[j] = qr*LCOLS + 4*qc;
    }

    // exact per-stage regions (output = staged rows [8,72) x cols [16,80)):
    // k1 rows [2,78) qc [2,22); k2 rows [4,76) qc [3,21);
    // k3 rows [6,74) qc [3,21); k4 rows [8,72) qc [4,20)
    const int rowlo[4] = {2, 4, 6, 8};
    const int rowhi[4] = {78, 76, 74, 72};
    const int qclo[4]  = {2, 3, 3, 4};
    const int qchi[4]  = {22, 21, 21, 20};
    const float csub_t[4] = {0.f, 0.25f, 0.25f, 0.5f};  // undo prev update
    const float cadd_t[4] = {0.25f, 0.25f, 0.5f, 0.f};  // apply this update
    const float wgt_t[4]  = {1.f, 2.f, 2.f, 1.f};

    stage_tile(bx, 0);          // prologue: first tile into buffer 0
    int cur = 0;

#pragma unroll 1
    for (int i = 0; i < TPB; ++i) {
        const int t  = bx + i*NBLK;
        const int tc = t & 15, tr = (t >> 4) & 15, bb = t >> 8;
        float* tu = lds + (cur ? 2*NFLD : 0);
        float* tv = tu + NFLD;

        asm volatile("s_waitcnt vmcnt(0)" ::: "memory");  // own prefetch done
        __syncthreads();                                  // tile i visible

        if (i + 1 < TPB) stage_tile(bx + (i+1)*NBLK, cur ^ 1);  // hide under compute

        f4 ku[NQ], kv[NQ], au[NQ], av[NQ];   // prev-stage k and RK accumulator
        f4 stu[NQ], stv[NQ];                 // LDS-write staging AND next center
#pragma unroll
        for (int j = 0; j < NQ; ++j) {
            ku[j] = z4; kv[j] = z4; au[j] = z4; av[j] = z4;
            stu[j] = z4; stv[j] = z4;
        }

        float* outu = out + (size_t)(bb*2) * plane;
        float* outv = outu + plane;

#pragma unroll
        for (int s = 0; s < 4; ++s) {
            const float wgt  = wgt_t[s];
            const float csub = csub_t[s];
            const float cadd = cadd_t[s];
            bool act[NQ];
#pragma unroll
            for (int j = 0; j < NQ; ++j) {
                act[j] = has[j] && qrA[j] >= rowlo[s] && qrA[j] < rowhi[s]
                                && qcA[j] >= qclo[s]  && qcA[j] < qchi[s];
                if (!act[j]) continue;
                const int l = lidx[j];
                f4 ucc, vcc;
                if (s == 0) { ucc = *(const f4*)(tu+l); vcc = *(const f4*)(tv+l); }
                else        { ucc = stu[j];             vcc = stv[j]; }
                f2 ul2 = *(const f2*)(tu+l-2);
                f2 ur2 = *(const f2*)(tu+l+4);
                f4 un1 = *(const f4*)(tu+l-LCOLS);
                f4 us1 = *(const f4*)(tu+l+LCOLS);
                f4 un2 = *(const f4*)(tu+l-2*LCOLS);
                f4 us2 = *(const f4*)(tu+l+2*LCOLS);
                f2 vl2 = *(const f2*)(tv+l-2);
                f2 vr2 = *(const f2*)(tv+l+4);
                f4 vn1 = *(const f4*)(tv+l-LCOLS);
                f4 vs1 = *(const f4*)(tv+l+LCOLS);
                f4 vn2 = *(const f4*)(tv+l-2*LCOLS);
                f4 vs2 = *(const f4*)(tv+l+2*LCOLS);
                float hu[8] = {ul2[0],ul2[1],ucc[0],ucc[1],ucc[2],ucc[3],ur2[0],ur2[1]};
                float hv[8] = {vl2[0],vl2[1],vcc[0],vcc[1],vcc[2],vcc[3],vr2[0],vr2[1]};
                f4 ou, ov;   // stage-3 output staging
#pragma unroll
                for (int k = 0; k < 4; ++k) {
                    float u = hu[k+2], v = hv[k+2];
                    // row-direction derivative (axis 2) = reference K_DX
                    float urow = d1*(us1[k]-un1[k]) + d2*(un2[k]-us2[k]);
                    float vrow = d1*(vs1[k]-vn1[k]) + d2*(vn2[k]-vs2[k]);
                    // col-direction derivative (axis 3) = reference K_DY
                    float ucol = d1*(hu[k+3]-hu[k+1]) + d2*(hu[k]-hu[k+4]);
                    float vcol = d1*(hv[k+3]-hv[k+1]) + d2*(hv[k]-hv[k+4]);
                    float ulap = a1*((un1[k]+us1[k])+(hu[k+1]+hu[k+3]))
                               + a2*((un2[k]+us2[k])+(hu[k]+hu[k+4])) + a0*u;
                    float vlap = a1*((vn1[k]+vs1[k])+(hv[k+1]+hv[k+3]))
                               + a2*((vn2[k]+vs2[k])+(hv[k]+hv[k+4])) + a0*v;
                    float fu = nu*ulap + UA*(u*urow) + UB*(v*ucol);
                    float fv = nu*vlap + VA*(u*vrow) + VB*(v*vcol);
                    float kuold = ku[j][k], kvold = kv[j][k];
                    if (s == 3) {
                        // u0 = t3 - DT*k3 ; out = u0 + (DT/6)*(k1+2k2+2k3+k4)
                        ou[k] = (u - 0.5f*kuold) + (1.f/12.f)*(au[j][k] + fu);
                        ov[k] = (v - 0.5f*kvold) + (1.f/12.f)*(av[j][k] + fv);
                    } else {
                        au[j][k] += wgt*fu;
                        av[j][k] += wgt*fv;
                        // t_{s+1} = u0 + cadd*k_new, u0 = t_s - csub*k_prev
                        stu[j][k] = (u - csub*kuold) + cadd*fu;
                        stv[j][k] = (v - csub*kvold) + cadd*fv;
                        ku[j][k] = fu;
                        kv[j][k] = fv;
                    }
                }
                if (s == 3) {
                    int gr = tr*64 + qrA[j] - 8;      // qr in [8,72) -> [0,64)
                    int gc = tc*64 + 4*qcA[j] - 16;   // qc in [4,20) -> [0,64)
                    *(f4*)(outu + (size_t)gr*1024 + gc) = ou;
                    *(f4*)(outv + (size_t)gr*1024 + gc) = ov;
                }
            }
            if (s < 3) {
                __syncthreads();   // all reads of t_s done
#pragma unroll
                for (int j = 0; j < NQ; ++j) {
                    if (!act[j]) continue;
                    *(f4*)(tu+lidx[j]) = stu[j];
                    *(f4*)(tv+lidx[j]) = stv[j];
                }
                __syncthreads();   // t_{s+1} visible
            }
        }
        cur ^= 1;
    }
}

extern "C" void kernel_launch(void* const* d_in, const int* in_sizes, int n_in,
                              void* d_out, int out_size, void* d_ws, size_t ws_size,
                              hipStream_t stream) {
    const float* h   = (const float*)d_in[0];
    const float* sRe = (const float*)d_in[1];
    const float* sUA = (const float*)d_in[2];
    const float* sUB = (const float*)d_in[3];
    const float* sVA = (const float*)d_in[4];
    const float* sVB = (const float*)d_in[5];
    float* o = (float*)d_out;

    static bool s_attr = false;
    if (!s_attr) {   // one-time opt-in for 128 KiB dynamic LDS (host API, not
                     // a stream op -- safe under graph capture)
        hipFuncSetAttribute((const void*)rk4_stencil,
                            hipFuncAttributeMaxDynamicSharedMemorySize,
                            4 * NFLD * (int)sizeof(float));
        s_attr = true;
    }
    rk4_stencil<<<dim3(NBLK,1,1), dim3(NT,1,1), 4*NFLD*sizeof(float), stream>>>(
        h, sRe, sUA, sUB, sVA, sVB, o);
}